// Round 1
// baseline (40878.244 us; speedup 1.0000x reference)
//
#include <hip/hip_runtime.h>
#include <hip/hip_fp16.h>
#include <stdint.h>

#define SEQ_LEN 16384
#define H       512
#define NWG     64      // workgroups (CUs used)
#define HK      8       // h elements owned per WG (H/NWG)
#define T       256     // threads per block
#define NROW    48      // rows per WG: 24 W_ih rows + 24 W_hh rows
#define WPITCH  257     // uints per row in LDS (256 data + 1 pad -> conflict-free)

// tagged element: high 32 bits = step tag (h_t has tag t), low 32 = f32 bits
__global__ void gru_init(unsigned long long* __restrict__ tagged) {
    int i = blockIdx.x * blockDim.x + threadIdx.x;
    if (i < H) {
        // buf0 holds h_0 = 0.0f with tag 0; buf1 invalid tag
        __hip_atomic_store(&tagged[i], 0ull, __ATOMIC_RELAXED, __HIP_MEMORY_SCOPE_AGENT);
        __hip_atomic_store(&tagged[H + i], 0xFFFFFFFF00000000ull, __ATOMIC_RELAXED, __HIP_MEMORY_SCOPE_AGENT);
    }
}

__launch_bounds__(T, 1)
__global__ void gru_main(const float* __restrict__ x,
                         const float* __restrict__ Wih,
                         const float* __restrict__ Whh,
                         const float* __restrict__ bih,
                         const float* __restrict__ bhh,
                         float* __restrict__ out,
                         unsigned long long* __restrict__ tagged)
{
    const int wg  = blockIdx.x;
    const int tid = threadIdx.x;
    const int j0  = wg * HK;

    __shared__ uint32_t w_lds[NROW * WPITCH];   // f16 pairs, padded pitch
    __shared__ float    x_lds[H];
    __shared__ float    h_lds[H];
    __shared__ float    partial[4 * NROW];
    __shared__ float    sums[NROW];
    __shared__ float    bsum[NROW];

    __half* wh = (__half*)w_lds;   // half index: row*(2*WPITCH) + k

    // ---- prologue: stage weights (f32 global -> f16 LDS) ----
    for (int idx = tid; idx < NROW * H; idx += T) {
        int r  = idx >> 9;          // local row 0..47
        int k  = idx & (H - 1);
        int rr = (r < 24) ? r : r - 24;
        int g  = rr >> 3;           // gate 0=r,1=z,2=n
        int jj = rr & 7;
        int grow = g * H + j0 + jj; // global row in [0,1536)
        float w = (r < 24) ? Wih[(size_t)grow * H + k] : Whh[(size_t)grow * H + k];
        wh[r * (2 * WPITCH) + k] = __float2half(w);
    }
    // biases: r,z biases fold into gi rows; n gate must keep b_hh_n inside r*h_n
    if (tid < NROW) {
        int r  = tid;
        int rr = (r < 24) ? r : r - 24;
        int g  = rr >> 3;
        int jj = rr & 7;
        int grow = g * H + j0 + jj;
        float b;
        if (r < 24) b = (g == 2) ? bih[grow] : (bih[grow] + bhh[grow]);
        else        b = (g == 2) ? bhh[grow] : 0.0f;
        bsum[r] = b;
    }

    // preload x_0 into regs
    float xr0 = x[2 * tid];
    float xr1 = x[2 * tid + 1];

    const int  row    = tid & 63;       // dot row slot (active if < 48)
    const int  c      = tid >> 6;       // chunk lane 0..3 (uniform per wave)
    const bool active = (row < NROW);
    const bool isGi   = (row < 24);

    for (int t = 0; t < SEQ_LEN; ++t) {
        // ---- phase 1: publish x_t to LDS; spin-acquire h_t (2 elems/thread) ----
        x_lds[2 * tid]     = xr0;
        x_lds[2 * tid + 1] = xr1;
        {
            unsigned long long* base = tagged + (size_t)(t & 1) * H;
            int e0 = 2 * tid, e1 = 2 * tid + 1;
            unsigned long long v;
            do { v = __hip_atomic_load(base + e0, __ATOMIC_RELAXED, __HIP_MEMORY_SCOPE_AGENT); }
            while ((uint32_t)(v >> 32) != (uint32_t)t);
            h_lds[e0] = __uint_as_float((uint32_t)v);
            do { v = __hip_atomic_load(base + e1, __ATOMIC_RELAXED, __HIP_MEMORY_SCOPE_AGENT); }
            while ((uint32_t)(v >> 32) != (uint32_t)t);
            h_lds[e1] = __uint_as_float((uint32_t)v);
        }
        __syncthreads();

        // ---- phase 3: dot products (48 rows x 512, f16 weights, f32 accum) ----
        float acc = 0.0f;
        if (active) {
            const float*     B    = isGi ? x_lds : h_lds;
            const uint32_t*  wrow = w_lds + row * WPITCH;
            #pragma unroll 8
            for (int i = 0; i < 64; ++i) {
                uint32_t wp = wrow[4 * i + c];           // halves k=8i+2c, 8i+2c+1
                float2  wf  = __half22float2(*(__half2*)&wp);
                int k = 8 * i + 2 * c;
                acc = fmaf(wf.x, B[k],     acc);
                acc = fmaf(wf.y, B[k + 1], acc);
            }
            partial[c * NROW + row] = acc;
        }

        // ---- phase 4: prefetch x_{t+1} into regs (latency hides under reduce) ----
        int tn = (t + 1 < SEQ_LEN) ? (t + 1) : 0;
        xr0 = x[(size_t)tn * H + 2 * tid];
        xr1 = x[(size_t)tn * H + 2 * tid + 1];
        __syncthreads();

        // ---- phase 6: reduce 4 chunk-partials + bias ----
        if (tid < NROW) {
            sums[tid] = partial[tid] + partial[NROW + tid] +
                        partial[2 * NROW + tid] + partial[3 * NROW + tid] + bsum[tid];
        }
        __syncthreads();

        // ---- phase 8: gates + publish h_{t+1} ----
        if (tid < HK) {
            int jj = tid;
            float ir  = sums[jj],        iz = sums[8 + jj],  inn = sums[16 + jj];
            float hr  = sums[24 + jj],   hz = sums[32 + jj], hn  = sums[40 + jj];
            float r_  = 1.0f / (1.0f + expf(-(ir + hr)));
            float z_  = 1.0f / (1.0f + expf(-(iz + hz)));
            float n_  = tanhf(inn + r_ * hn);
            float hold = h_lds[j0 + jj];
            float hnew = (1.0f - z_) * n_ + z_ * hold;
            out[(size_t)t * H + j0 + jj] = hnew;
            unsigned long long pv =
                ((unsigned long long)(uint32_t)(t + 1) << 32) |
                (unsigned long long)__float_as_uint(hnew);
            __hip_atomic_store(tagged + (size_t)((t + 1) & 1) * H + j0 + jj, pv,
                               __ATOMIC_RELAXED, __HIP_MEMORY_SCOPE_AGENT);
        }
        // no barrier needed here: next-iter h_lds/x_lds writes are gated by the
        // tag spin (which transitively orders after every WG's phase-8), and all
        // other LDS reuse is separated by the phase-2/5/7 barriers.
    }
}

extern "C" void kernel_launch(void* const* d_in, const int* in_sizes, int n_in,
                              void* d_out, int out_size, void* d_ws, size_t ws_size,
                              hipStream_t stream) {
    const float* x   = (const float*)d_in[0];
    const float* Wih = (const float*)d_in[1];
    const float* Whh = (const float*)d_in[2];
    const float* bih = (const float*)d_in[3];
    const float* bhh = (const float*)d_in[4];
    float* out = (float*)d_out;
    unsigned long long* tagged = (unsigned long long*)d_ws;  // 2*512*8 = 8 KB

    gru_init<<<2, 256, 0, stream>>>(tagged);
    gru_main<<<NWG, T, 0, stream>>>(x, Wih, Whh, bih, bhh, out, tagged);
}